// Round 1
// baseline (57.346 us; speedup 1.0000x reference)
//
#include <hip/hip_runtime.h>

#define SSIM_C1 0.2f

// 1 - ssim for a block sum pair, with the reference's faithful "bug":
// mu = block_sum / h (side length, not h*h).
__device__ __forceinline__ float loss_term(float sx, float sy, float inv_h) {
    float mx = sx * inv_h;
    float my = sy * inv_h;
    float num = 2.0f * mx * my + SSIM_C1;
    float den = mx * mx + my * my + SSIM_C1;   // >= C1 > 0, rcp safe
    return 1.0f - num * __builtin_amdgcn_rcpf(den);
}

// Weights w_d = 0.25^d * K_LOSS[d],  K_LOSS = [9,8,7,6,5,4,3,2,1]
// d=8: 1/65536*1   d=7: 2/16384   d=6: 3/4096   d=5: 4/1024   d=4: 5/256
// d=3: 6/64        d=2: 7/16      d=1: 8/4      d=0: 9

// Kernel 1: 64 blocks (8x8 tiles of 32x32), 256 threads each.
// Each thread owns a 2x2 quad: depth 8 (per-pixel) + depth 7 (quad).
// LDS tree pooling for depths 6..3. Writes depth-3 tile sums + loss partial.
__global__ __launch_bounds__(256) void loss_tree_k1(
    const float* __restrict__ x, const float* __restrict__ y,
    float* __restrict__ wsx, float* __restrict__ wsy,
    float* __restrict__ partial)
{
    __shared__ float LSx[256], LSy[256];
    __shared__ float LBx[64], LBy[64];
    __shared__ float red[4];

    const int bid = blockIdx.x;        // 0..63
    const int tid = threadIdx.x;       // 0..255
    const int tile_r = bid >> 3, tile_c = bid & 7;
    const int qr = tid >> 4, qc = tid & 15;          // 16x16 quads per tile
    const int row = tile_r * 32 + qr * 2;
    const int col = tile_c * 32 + qc * 2;

    const float2* x2 = (const float2*)x;
    const float2* y2 = (const float2*)y;
    const int idx0 = (row * 256 + col) >> 1;
    const int idx1 = ((row + 1) * 256 + col) >> 1;
    float2 xa = x2[idx0], xb = x2[idx1];
    float2 ya = y2[idx0], yb = y2[idx1];

    float acc = 0.0f;
    // d=8: h=1, w=1/65536
    acc += 1.52587890625e-05f * (loss_term(xa.x, ya.x, 1.0f) +
                                 loss_term(xa.y, ya.y, 1.0f) +
                                 loss_term(xb.x, yb.x, 1.0f) +
                                 loss_term(xb.y, yb.y, 1.0f));
    // d=7: h=2, w=2/16384
    float qx = xa.x + xa.y + xb.x + xb.y;
    float qy = ya.x + ya.y + yb.x + yb.y;
    acc += 1.220703125e-04f * loss_term(qx, qy, 0.5f);

    LSx[tid] = qx; LSy[tid] = qy;
    __syncthreads();

    // d=6: 8x8 from 16x16, h=4, w=3/4096
    if (tid < 64) {
        int r = tid >> 3, c = tid & 7;
        int i0 = (r * 2) * 16 + c * 2;
        float sx = LSx[i0] + LSx[i0 + 1] + LSx[i0 + 16] + LSx[i0 + 17];
        float sy = LSy[i0] + LSy[i0 + 1] + LSy[i0 + 16] + LSy[i0 + 17];
        acc += 7.32421875e-04f * loss_term(sx, sy, 0.25f);
        LBx[tid] = sx; LBy[tid] = sy;
    }
    __syncthreads();

    // d=5: 4x4 from 8x8, h=8, w=4/1024
    if (tid < 16) {
        int r = tid >> 2, c = tid & 3;
        int i0 = (r * 2) * 8 + c * 2;
        float sx = LBx[i0] + LBx[i0 + 1] + LBx[i0 + 8] + LBx[i0 + 9];
        float sy = LBy[i0] + LBy[i0 + 1] + LBy[i0 + 8] + LBy[i0 + 9];
        acc += 3.90625e-03f * loss_term(sx, sy, 0.125f);
        LSx[tid] = sx; LSy[tid] = sy;
    }
    __syncthreads();

    // d=4: 2x2 from 4x4, h=16, w=5/256
    if (tid < 4) {
        int r = tid >> 1, c = tid & 1;
        int i0 = (r * 2) * 4 + c * 2;
        float sx = LSx[i0] + LSx[i0 + 1] + LSx[i0 + 4] + LSx[i0 + 5];
        float sy = LSy[i0] + LSy[i0 + 1] + LSy[i0 + 4] + LSy[i0 + 5];
        acc += 1.953125e-02f * loss_term(sx, sy, 0.0625f);
        LBx[tid] = sx; LBy[tid] = sy;
    }
    __syncthreads();

    // d=3: tile sum (side 32), h=32, w=6/64
    if (tid == 0) {
        float sx = LBx[0] + LBx[1] + LBx[2] + LBx[3];
        float sy = LBy[0] + LBy[1] + LBy[2] + LBy[3];
        acc += 9.375e-02f * loss_term(sx, sy, 0.03125f);
        wsx[bid] = sx; wsy[bid] = sy;
    }

    // block-wide reduction of acc (4 waves)
    #pragma unroll
    for (int o = 32; o >= 1; o >>= 1) acc += __shfl_xor(acc, o, 64);
    if ((tid & 63) == 0) red[tid >> 6] = acc;
    __syncthreads();
    if (tid == 0) partial[bid] = red[0] + red[1] + red[2] + red[3];
}

// Kernel 2: one wave. Lane i holds tile (r=i>>3, c=i&7) depth-3 sums.
// Shuffle-pool depths 2..0, add loss partials, write scalar.
__global__ __launch_bounds__(64) void loss_tree_k2(
    const float* __restrict__ wsx, const float* __restrict__ wsy,
    const float* __restrict__ partial, float* __restrict__ out)
{
    const int lane = threadIdx.x;
    float sx = wsx[lane], sy = wsy[lane];
    float acc = partial[lane];

    // d=2: pool over bit0 (col) + bit3 (row) -> side-64 sums, h=64, w=7/16
    sx += __shfl_xor(sx, 1, 64); sy += __shfl_xor(sy, 1, 64);
    sx += __shfl_xor(sx, 8, 64); sy += __shfl_xor(sy, 8, 64);
    if ((lane & 9) == 0)  acc += 0.4375f * loss_term(sx, sy, 1.0f / 64.0f);

    // d=1: pool over bit1 + bit4 -> side-128 sums, h=128, w=8/4
    sx += __shfl_xor(sx, 2, 64);  sy += __shfl_xor(sy, 2, 64);
    sx += __shfl_xor(sx, 16, 64); sy += __shfl_xor(sy, 16, 64);
    if ((lane & 27) == 0) acc += 2.0f * loss_term(sx, sy, 1.0f / 128.0f);

    // d=0: pool over bit2 + bit5 -> full sum, h=256, w=9
    sx += __shfl_xor(sx, 4, 64);  sy += __shfl_xor(sy, 4, 64);
    sx += __shfl_xor(sx, 32, 64); sy += __shfl_xor(sy, 32, 64);
    if (lane == 0) acc += 9.0f * loss_term(sx, sy, 1.0f / 256.0f);

    // final reduction of loss partials
    #pragma unroll
    for (int o = 32; o >= 1; o >>= 1) acc += __shfl_xor(acc, o, 64);
    if (lane == 0) out[0] = acc;
}

extern "C" void kernel_launch(void* const* d_in, const int* in_sizes, int n_in,
                              void* d_out, int out_size, void* d_ws, size_t ws_size,
                              hipStream_t stream) {
    const float* x = (const float*)d_in[0];
    const float* y = (const float*)d_in[1];
    float* ws = (float*)d_ws;
    float* wsx = ws;            // 64 tile sums (x)
    float* wsy = ws + 64;       // 64 tile sums (y)
    float* partial = ws + 128;  // 64 loss partials

    loss_tree_k1<<<64, 256, 0, stream>>>(x, y, wsx, wsy, partial);
    loss_tree_k2<<<1, 64, 0, stream>>>(wsx, wsy, partial, (float*)d_out);
}